// Round 3
// baseline (801.661 us; speedup 1.0000x reference)
//
#include <hip/hip_runtime.h>
#include <hip/hip_bf16.h>
#include <hip/hip_fp16.h>

typedef _Float16 f16;
typedef __attribute__((ext_vector_type(8))) _Float16 f16x8;
typedef __attribute__((ext_vector_type(4))) _Float16 f16x4;
typedef __attribute__((ext_vector_type(2))) _Float16 f16x2;
typedef __attribute__((ext_vector_type(4))) float f32x4;

#define AS1(p) ((const __attribute__((address_space(1))) void*)(p))
#define AS3(p) ((__attribute__((address_space(3))) void*)(p))

// ---------------- weight fp32 -> f16 conversion (concatenated) ----------------
__global__ __launch_bounds__(256) void cvt_weights(
    const float* __restrict__ wq, const float* __restrict__ wp,
    const float* __restrict__ wf1, const float* __restrict__ wf2,
    f16* __restrict__ o) {
  int i = blockIdx.x * 256 + threadIdx.x;  // grid sized exactly 786432
  float v;
  if (i < 196608)       v = wq[i];
  else if (i < 262144)  v = wp[i - 196608];
  else if (i < 524288)  v = wf1[i - 262144];
  else                  v = wf2[i - 524288];
  o[i] = (f16)v;
}

// ---------------- bias table -> MFMA fragment-lane order, pre-scaled by log2e ----
// T[h][lane][i*16+j*4+r] = bias[idx(n,m)][h] * log2e, n=16i+4*(lane>>4)+r, m=16j+(lane&15)
__global__ __launch_bounds__(256) void prep_bias(
    const float* __restrict__ bt, float* __restrict__ T) {
  const int flat = blockIdx.x * 256 + threadIdx.x;   // grid = 128 -> 32768
  const int h = flat >> 12, l = (flat >> 6) & 63, s = flat & 63;
  const int i = s >> 4, j = (s >> 2) & 3, r = s & 3;
  const int n = 16 * i + 4 * (l >> 4) + r;
  const int m = 16 * j + (l & 15);
  const int idx = ((n >> 3) - (m >> 3) + 7) * 15 + ((n & 7) - (m & 7) + 7);
  T[flat] = bt[idx * 8 + h] * 1.4426950408889634f;
}

// ---------------- LayerNorm (one wave per 256-elem row) ----------------
// PART=true: write window-partitioned order; PART=false: natural row order
template<bool PART, typename TIN>
__global__ __launch_bounds__(256) void ln_rows(
    const TIN* __restrict__ x, const float* __restrict__ g,
    const float* __restrict__ b, f16* __restrict__ out) {
  const int t = blockIdx.x * 4 + (threadIdx.x >> 6);   // token row within chunk
  const int lane = threadIdx.x & 63;
  float v0, v1, v2, v3;
  if constexpr (sizeof(TIN) == 4) {
    const float4 v = ((const float4*)(x + (long)t * 256))[lane];
    v0 = v.x; v1 = v.y; v2 = v.z; v3 = v.w;
  } else {
    const f16x4 v = ((const f16x4*)(x + (long)t * 256))[lane];
    v0 = (float)v[0]; v1 = (float)v[1]; v2 = (float)v[2]; v3 = (float)v[3];
  }
  float s  = v0 + v1 + v2 + v3;
  float ss = v0*v0 + v1*v1 + v2*v2 + v3*v3;
  #pragma unroll
  for (int off = 32; off; off >>= 1) {
    s  += __shfl_xor(s, off);
    ss += __shfl_xor(ss, off);
  }
  const float mu = s * (1.0f / 256.0f);
  const float var = ss * (1.0f / 256.0f) - mu * mu;
  const float rs = rsqrtf(var + 1e-5f);
  const float4 gv = ((const float4*)g)[lane];
  const float4 bv = ((const float4*)b)[lane];
  long row;
  if (PART) {
    const int bI = t >> 12, l = t & 4095;
    const int hh = l >> 6, w2 = l & 63;
    const int wi = bI * 64 + (hh >> 3) * 8 + (w2 >> 3);
    const int n  = (hh & 7) * 8 + (w2 & 7);
    row = (long)wi * 64 + n;
  } else {
    row = t;
  }
  f16x4 o4;
  o4[0] = (f16)((v0 - mu) * rs * gv.x + bv.x);
  o4[1] = (f16)((v1 - mu) * rs * gv.y + bv.y);
  o4[2] = (f16)((v2 - mu) * rs * gv.z + bv.z);
  o4[3] = (f16)((v3 - mu) * rs * gv.w + bv.w);
  *(f16x4*)(out + row * 256 + lane * 4) = o4;
}

// ---------------- GEMM: C[M,N] = A[M,K] @ Bw[N,K]^T + bias, fused epilogues ----------------
// EPI 0: f16 out = v                               (qkv)
// EPI 1: f16 out[window-reversed row] = x + v      (proj -> x1 f16), resid fp32
// EPI 2: f16 out = gelu_exact(v)                   (fc1)
// EPI 3: f32 out = x1h + v                         (fc2 + residual, final), resid f16
// XCD-contiguous block remap; double-buffered K-loop (stage next tile before
// compute of current, one vmcnt(0)+barrier per tile); LDS stage layout XOR-
// swizzled both-sides (pre-swizzled global src + swizzled fragment read) so
// ds_read_b128 fragment loads are bank-conflict-free (2-way max).
template<int EPI, int K>
__global__ __launch_bounds__(256) void gemm_bt(
    const f16* __restrict__ A, const f16* __restrict__ Bw,
    const float* __restrict__ bias, const float* __restrict__ residf,
    const f16* __restrict__ residh,
    f16* __restrict__ outh, float* __restrict__ outf, int N) {
  __shared__ f16 As[2][128 * 32];
  __shared__ f16 Bs[2][128 * 32];
  const int tid  = threadIdx.x;
  const int wid  = tid >> 6;
  const int lane = tid & 63;
  const int qd   = lane >> 4;       // quad 0..3
  const int l16  = lane & 15;
  // XCD-aware swizzle (nwg is always a multiple of 8 here)
  const int gx  = gridDim.x;
  const int nwg = gx * gridDim.y;
  const int g   = blockIdx.y * gx + blockIdx.x;
  const int gs  = (g & 7) * (nwg >> 3) + (g >> 3);
  const long tM = (long)(gs / gx) * 128;
  const int  tN = (gs % gx) * 128;
  const int srow = lane >> 2;       // 0..15
  // stage-side swizzle: column chunk XOR'd by (srow>>1)&3 (both-sides with read)
  const int scol = ((lane & 3) ^ ((srow >> 1) & 3)) * 8;  // pre-swizzled global col
  const int wm = (wid >> 1) * 64;
  const int wn = (wid & 1) * 64;
  const int rsw = (l16 >> 1) & 3;   // read-side swizzle for fragment loads

  f32x4 acc[4][4];
  #pragma unroll
  for (int i = 0; i < 4; ++i)
    #pragma unroll
    for (int j = 0; j < 4; ++j) acc[i][j] = (f32x4){0.f, 0.f, 0.f, 0.f};

  const int nt = K / 32;

  // prologue: stage tile 0
  #pragma unroll
  for (int t = 0; t < 2; ++t) {
    const int gidx = wid * 2 + t;
    const int row  = gidx * 16 + srow;
    __builtin_amdgcn_global_load_lds(AS1(A + (tM + row) * K + scol),
                                     AS3(&As[0][gidx * 512]), 16, 0, 0);
    __builtin_amdgcn_global_load_lds(AS1(Bw + (long)(tN + row) * K + scol),
                                     AS3(&Bs[0][gidx * 512]), 16, 0, 0);
  }
  asm volatile("s_waitcnt vmcnt(0)" ::: "memory");
  __builtin_amdgcn_s_barrier();

  int cur = 0;
  for (int t = 0; t < nt; ++t) {
    // issue next-tile stage before compute of current (latency hides under MFMA)
    if (t + 1 < nt) {
      const int k0 = (t + 1) * 32;
      #pragma unroll
      for (int u = 0; u < 2; ++u) {
        const int gidx = wid * 2 + u;
        const int row  = gidx * 16 + srow;
        __builtin_amdgcn_global_load_lds(AS1(A + (tM + row) * K + k0 + scol),
                                         AS3(&As[cur ^ 1][gidx * 512]), 16, 0, 0);
        __builtin_amdgcn_global_load_lds(AS1(Bw + (long)(tN + row) * K + k0 + scol),
                                         AS3(&Bs[cur ^ 1][gidx * 512]), 16, 0, 0);
      }
    }
    f16x8 af[4], bf[4];
    #pragma unroll
    for (int i = 0; i < 4; ++i)
      af[i] = *(const f16x8*)&As[cur][(wm + i * 16 + l16) * 32 + ((qd ^ rsw) * 8)];
    #pragma unroll
    for (int j = 0; j < 4; ++j)
      bf[j] = *(const f16x8*)&Bs[cur][(wn + j * 16 + l16) * 32 + ((qd ^ rsw) * 8)];
    #pragma unroll
    for (int i = 0; i < 4; ++i)
      #pragma unroll
      for (int j = 0; j < 4; ++j)
        acc[i][j] = __builtin_amdgcn_mfma_f32_16x16x32_f16(af[i], bf[j], acc[i][j], 0, 0, 0);
    asm volatile("s_waitcnt vmcnt(0)" ::: "memory");
    __builtin_amdgcn_s_barrier();
    cur ^= 1;
  }

  float bb[4];
  #pragma unroll
  for (int j = 0; j < 4; ++j) bb[j] = bias[tN + wn + j * 16 + l16];

  if (EPI == 3) {
    #pragma unroll
    for (int j = 0; j < 4; ++j) {
      const int col = tN + wn + j * 16 + l16;
      #pragma unroll
      for (int i = 0; i < 4; ++i) {
        #pragma unroll
        for (int r = 0; r < 4; ++r) {
          const long row = tM + wm + i * 16 + qd * 4 + r;
          const long off = row * 256 + col;
          outf[off] = (float)residh[off] + acc[i][j][r] + bb[j];
        }
      }
    }
  } else {
    // LDS-staged f16 epilogue; col XOR-swizzled by row to break 4-way write conflicts
    f16* slice = &As[0][0] + wid * 1024;  // per-wave 16x64 tile (2 KB)
    const int rrow = lane >> 3;          // 0..7
    const int seg  = lane & 7;           // 0..7
    #pragma unroll
    for (int i = 0; i < 4; ++i) {
      #pragma unroll
      for (int j = 0; j < 4; ++j) {
        #pragma unroll
        for (int r = 0; r < 4; ++r) {
          float v = acc[i][j][r] + bb[j];
          if (EPI == 2) v = 0.5f * v * (1.0f + erff(v * 0.70710678118654752f));
          const int r16 = qd * 4 + r;
          slice[r16 * 64 + ((j * 16 + l16) ^ ((r16 & 7) << 3))] = (f16)v;
        }
      }
      __syncthreads();
      #pragma unroll
      for (int hrow = 0; hrow < 16; hrow += 8) {
        const int lrow = hrow + rrow;                       // 0..15
        const f16x8 v8 = *(const f16x8*)(slice + lrow * 64 + (seg ^ (lrow & 7)) * 8);
        const long grow = tM + wm + i * 16 + lrow;
        const int  gc   = tN + wn + seg * 8;
        if (EPI == 1) {
          const int rw = (int)grow;
          const int wi = rw >> 6, n = rw & 63;
          const int bI = wi >> 6, wloc = wi & 63;
          const int hh = (wloc >> 3) * 8 + (n >> 3);
          const int w2 = (wloc & 7) * 8 + (n & 7);
          const long prow = (long)bI * 4096 + hh * 64 + w2;
          const float* rp = residf + prow * 256 + gc;
          f16x8 o;
          #pragma unroll
          for (int k = 0; k < 8; ++k) o[k] = (f16)(rp[k] + (float)v8[k]);
          *(f16x8*)(outh + prow * 256 + gc) = o;
        } else {
          *(f16x8*)(outh + grow * N + gc) = v8;
        }
      }
      __syncthreads();
    }
  }
}

// ---------------- windowed attention: MFMA flash, one wave per (window, head) ----------------
// Per-wave private LDS slab (no __syncthreads needed):
//   [0, 4608)     : V^T f16, 32 rows (d) x stride 144B (72 f16), holds 64 m values/row
//   [4608, 12800) : P f16 64x64, row stride 128B, XOR-swizzled by ((row&7)<<4);
//                   later overlaid by O f16 64x32, row stride 80B
__global__ __launch_bounds__(256, 3) void attn_win(
    const f16* __restrict__ qkv, const float* __restrict__ bt,  // bt = T[8][64][64] pre-scaled
    f16* __restrict__ out) {
  __shared__ __align__(16) char SMEM[4 * 12800];
  const int wid = threadIdx.x >> 6, lane = threadIdx.x & 63;
  const int qd = lane >> 4, l16 = lane & 15;
  const int unit = blockIdx.x * 4 + wid;   // (window,head) unit within chunk
  const int wi = unit >> 3, h = unit & 7;
  char* W = SMEM + wid * 12800;
  f16* VT = (f16*)W;               // stride 72 f16 per d-row
  char* Pb = W + 4608;

  const f16* qbase = qkv + (long)wi * 64 * 768 + h * 32;

  // ---- Q/K fragments straight from global in MFMA A/B layout ----
  f16x8 qa[4], kb[4];
  #pragma unroll
  for (int i = 0; i < 4; ++i)
    qa[i] = *(const f16x8*)(qbase + (16 * i + l16) * 768 + qd * 8);
  #pragma unroll
  for (int j = 0; j < 4; ++j)
    kb[j] = *(const f16x8*)(qbase + 256 + (16 * j + l16) * 768 + qd * 8);

  // ---- stage V transposed into LDS: VT[d][m] ----
  #pragma unroll
  for (int it = 0; it < 4; ++it) {
    const f16x8 v8 = *(const f16x8*)(qbase + 512 + (16 * it + l16) * 768 + qd * 8);
    #pragma unroll
    for (int e = 0; e < 8; ++e)
      VT[(qd * 8 + e) * 72 + 16 * it + l16] = v8[e];
  }

  // ---- QK^T: S[n][m], C-layout: n = 16i+4qd+r, m = 16j+l16 ----
  f32x4 S[4][4];
  #pragma unroll
  for (int i = 0; i < 4; ++i)
    #pragma unroll
    for (int j = 0; j < 4; ++j) S[i][j] = (f32x4){0.f, 0.f, 0.f, 0.f};
  #pragma unroll
  for (int i = 0; i < 4; ++i)
    #pragma unroll
    for (int j = 0; j < 4; ++j)
      S[i][j] = __builtin_amdgcn_mfma_f32_16x16x32_f16(qa[i], kb[j], S[i][j], 0, 0, 0);

  // ---- scale (log2e folded) + bias from lane-ordered table ----
  const float SC = 0.17677669529663687f * 1.4426950408889634f;  // 1/sqrt(32)*log2e
  const float* Tb = bt + ((h * 64 + lane) << 6);
  #pragma unroll
  for (int i = 0; i < 4; ++i) {
    f32x4 b0 = *(const f32x4*)(Tb + i * 16);
    f32x4 b1 = *(const f32x4*)(Tb + i * 16 + 4);
    f32x4 b2 = *(const f32x4*)(Tb + i * 16 + 8);
    f32x4 b3 = *(const f32x4*)(Tb + i * 16 + 12);
    #pragma unroll
    for (int r = 0; r < 4; ++r) {
      S[i][0][r] = S[i][0][r] * SC + b0[r];
      S[i][1][r] = S[i][1][r] * SC + b1[r];
      S[i][2][r] = S[i][2][r] * SC + b2[r];
      S[i][3][r] = S[i][3][r] * SC + b3[r];
    }
  }

  // ---- softmax over m (cols): in-lane j-reduce + 16-lane butterfly ----
  float inv[4][4];
  #pragma unroll
  for (int i = 0; i < 4; ++i) {
    #pragma unroll
    for (int r = 0; r < 4; ++r) {
      float mx = fmaxf(fmaxf(S[i][0][r], S[i][1][r]), fmaxf(S[i][2][r], S[i][3][r]));
      #pragma unroll
      for (int msk = 1; msk < 16; msk <<= 1) mx = fmaxf(mx, __shfl_xor(mx, msk));
      float s0 = 0.f;
      #pragma unroll
      for (int j = 0; j < 4; ++j) {
        const float p = __builtin_amdgcn_exp2f(S[i][j][r] - mx);
        S[i][j][r] = p;
        s0 += p;
      }
      #pragma unroll
      for (int msk = 1; msk < 16; msk <<= 1) s0 += __shfl_xor(s0, msk);
      inv[i][r] = __builtin_amdgcn_rcpf(s0);
    }
  }

  // ---- P -> LDS f16 (unnormalized, <=1), XOR-swizzled by row ----
  #pragma unroll
  for (int i = 0; i < 4; ++i) {
    #pragma unroll
    for (int r = 0; r < 4; ++r) {
      const int n = 16 * i + 4 * qd + r;
      char* rowp = Pb + n * 128;
      const int sw = (n & 7) << 4;
      #pragma unroll
      for (int j = 0; j < 4; ++j)
        *(f16*)(rowp + ((j * 32 + l16 * 2) ^ sw)) = (f16)S[i][j][r];
    }
  }

  // ---- PV: O[64,32] = P @ V, A = P rows (LDS), B = V via VT rows (LDS) ----
  f32x4 O[4][2];
  #pragma unroll
  for (int i = 0; i < 4; ++i) {
    O[i][0] = (f32x4){0.f, 0.f, 0.f, 0.f};
    O[i][1] = (f32x4){0.f, 0.f, 0.f, 0.f};
  }
  #pragma unroll
  for (int kk = 0; kk < 2; ++kk) {
    f16x8 vb[2];
    #pragma unroll
    for (int jj = 0; jj < 2; ++jj)
      vb[jj] = *(const f16x8*)((const char*)W + (16 * jj + l16) * 144 + kk * 64 + qd * 16);
    #pragma unroll
    for (int i = 0; i < 4; ++i) {
      const f16x8 pa = *(const f16x8*)(Pb + (16 * i + l16) * 128 +
                                       ((kk * 64 + qd * 16) ^ ((l16 & 7) << 4)));
      #pragma unroll
      for (int jj = 0; jj < 2; ++jj)
        O[i][jj] = __builtin_amdgcn_mfma_f32_16x16x32_f16(pa, vb[jj], O[i][jj], 0, 0, 0);
    }
  }

  // ---- normalize (in-lane: same (i,qd,r) slot layout), stage O in LDS, store coalesced ----
  #pragma unroll
  for (int i = 0; i < 4; ++i) {
    #pragma unroll
    for (int jj = 0; jj < 2; ++jj) {
      #pragma unroll
      for (int r = 0; r < 4; ++r) {
        const int n = 16 * i + 4 * qd + r;
        *(f16*)(Pb + n * 80 + jj * 32 + l16 * 2) = (f16)(O[i][jj][r] * inv[i][r]);
      }
    }
  }
  #pragma unroll
  for (int it = 0; it < 4; ++it) {
    const int row = 16 * it + l16;
    const f16x8 o8 = *(const f16x8*)(Pb + row * 80 + qd * 16);
    *(f16x8*)(out + ((long)wi * 64 + row) * 256 + h * 32 + qd * 8) = o8;
  }
}

// ---------------- launch ----------------
extern "C" void kernel_launch(void* const* d_in, const int* in_sizes, int n_in,
                              void* d_out, int out_size, void* d_ws, size_t ws_size,
                              hipStream_t stream) {
  const float* x     = (const float*)d_in[0];
  const float* g1    = (const float*)d_in[2];
  const float* b1    = (const float*)d_in[3];
  const float* wqkv  = (const float*)d_in[4];
  const float* bqkv  = (const float*)d_in[5];
  const float* btab  = (const float*)d_in[6];
  const float* wproj = (const float*)d_in[7];
  const float* bproj = (const float*)d_in[8];
  const float* g2    = (const float*)d_in[9];
  const float* b2    = (const float*)d_in[10];
  const float* wfc1  = (const float*)d_in[11];
  const float* bfc1  = (const float*)d_in[12];
  const float* wfc2  = (const float*)d_in[13];
  const float* bfc2  = (const float*)d_in[14];
  float* out = (float*)d_out;

  char* ws = (char*)d_ws;
  // weights f16: 786432 elems = 1.5 MB at ws[0, 1.5MB); bias table T at [1.5MB, 1.625MB)
  f16* wgt   = (f16*)ws;
  f16* wq16  = wgt;
  f16* wp16  = wgt + 196608;
  f16* wf116 = wgt + 262144;
  f16* wf216 = wgt + 524288;
  float* Tbuf = (float*)(ws + 1572864);   // 8*64*64 f32 = 128 KB

  // Per-image f16 buffers: xn 2MB | qkv 6MB | x1 2MB | xn2 2MB ; h (8MB) reuses xn+qkv.
  int CH = 1;
  for (int cand = 32; cand >= 1; cand >>= 1) {
    const size_t need = 2097152ULL + (size_t)cand * 12582912ULL;
    if (need <= ws_size) { CH = cand; break; }
  }
  const int NC = 32 / CH;

  const size_t O_xn  = 2097152ULL;
  const size_t O_qkv = O_xn  + (size_t)CH * 2097152ULL;
  const size_t O_x1  = O_qkv + (size_t)CH * 6291456ULL;
  const size_t O_xn2 = O_x1  + (size_t)CH * 2097152ULL;
  f16* xnw  = (f16*)(ws + O_xn);    // ln1 out / attn out
  f16* qkvb = (f16*)(ws + O_qkv);
  f16* x1h  = (f16*)(ws + O_x1);
  f16* xn2  = (f16*)(ws + O_xn2);
  f16* hbuf = (f16*)(ws + O_xn);    // fc1 out: reuses xn+qkv (exactly CH*8MB)

  cvt_weights<<<3072, 256, 0, stream>>>(wqkv, wproj, wfc1, wfc2, wgt);
  prep_bias<<<128, 256, 0, stream>>>(btab, Tbuf);

  const long imgElems = 4096L * 256;   // fp32 elems per image
  for (int c = 0; c < NC; ++c) {
    const float* xc  = x   + (long)c * CH * imgElems;
    float*       oc  = out + (long)c * CH * imgElems;
    ln_rows<true, float><<<CH * 1024, 256, 0, stream>>>(xc, g1, b1, xnw);
    gemm_bt<0, 256><<<dim3(6, CH * 32), 256, 0, stream>>>(xnw, wq16, bqkv, nullptr, nullptr, qkvb, nullptr, 768);
    attn_win<<<CH * 128, 256, 0, stream>>>(qkvb, Tbuf, xnw);
    gemm_bt<1, 256><<<dim3(2, CH * 32), 256, 0, stream>>>(xnw, wp16, bproj, xc, nullptr, x1h, nullptr, 256);
    ln_rows<false, f16><<<CH * 1024, 256, 0, stream>>>(x1h, g2, b2, xn2);
    gemm_bt<2, 256><<<dim3(8, CH * 32), 256, 0, stream>>>(xn2, wf116, bfc1, nullptr, nullptr, hbuf, nullptr, 1024);
    gemm_bt<3, 1024><<<dim3(2, CH * 32), 256, 0, stream>>>(hbuf, wf216, bfc2, nullptr, x1h, nullptr, oc, 256);
  }
}

// Round 5
// 781.241 us; speedup vs baseline: 1.0261x; 1.0261x over previous
//
#include <hip/hip_runtime.h>
#include <hip/hip_bf16.h>
#include <hip/hip_fp16.h>

typedef _Float16 f16;
typedef __attribute__((ext_vector_type(8))) _Float16 f16x8;
typedef __attribute__((ext_vector_type(4))) _Float16 f16x4;
typedef __attribute__((ext_vector_type(2))) _Float16 f16x2;
typedef __attribute__((ext_vector_type(4))) float f32x4;

#define AS1(p) ((const __attribute__((address_space(1))) void*)(p))
#define AS3(p) ((__attribute__((address_space(3))) void*)(p))

// ---------------- weight fp32 -> f16 conversion (concatenated) ----------------
__global__ __launch_bounds__(256) void cvt_weights(
    const float* __restrict__ wq, const float* __restrict__ wp,
    const float* __restrict__ wf1, const float* __restrict__ wf2,
    f16* __restrict__ o) {
  int i = blockIdx.x * 256 + threadIdx.x;  // grid sized exactly 786432
  float v;
  if (i < 196608)       v = wq[i];
  else if (i < 262144)  v = wp[i - 196608];
  else if (i < 524288)  v = wf1[i - 262144];
  else                  v = wf2[i - 524288];
  o[i] = (f16)v;
}

// ---------------- bias table -> MFMA fragment-lane order, pre-scaled by log2e ----
// T[h][lane][i*16+j*4+r] = bias[idx(n,m)][h] * log2e, n=16i+4*(lane>>4)+r, m=16j+(lane&15)
__global__ __launch_bounds__(256) void prep_bias(
    const float* __restrict__ bt, float* __restrict__ T) {
  const int flat = blockIdx.x * 256 + threadIdx.x;   // grid = 128 -> 32768
  const int h = flat >> 12, l = (flat >> 6) & 63, s = flat & 63;
  const int i = s >> 4, j = (s >> 2) & 3, r = s & 3;
  const int n = 16 * i + 4 * (l >> 4) + r;
  const int m = 16 * j + (l & 15);
  const int idx = ((n >> 3) - (m >> 3) + 7) * 15 + ((n & 7) - (m & 7) + 7);
  T[flat] = bt[idx * 8 + h] * 1.4426950408889634f;
}

// ---------------- LayerNorm (one wave per 256-elem row) ----------------
// PART=true: write window-partitioned order; PART=false: natural row order
template<bool PART, typename TIN>
__global__ __launch_bounds__(256) void ln_rows(
    const TIN* __restrict__ x, const float* __restrict__ g,
    const float* __restrict__ b, f16* __restrict__ out) {
  const int t = blockIdx.x * 4 + (threadIdx.x >> 6);   // token row within chunk
  const int lane = threadIdx.x & 63;
  float v0, v1, v2, v3;
  if constexpr (sizeof(TIN) == 4) {
    const float4 v = ((const float4*)(x + (long)t * 256))[lane];
    v0 = v.x; v1 = v.y; v2 = v.z; v3 = v.w;
  } else {
    const f16x4 v = ((const f16x4*)(x + (long)t * 256))[lane];
    v0 = (float)v[0]; v1 = (float)v[1]; v2 = (float)v[2]; v3 = (float)v[3];
  }
  float s  = v0 + v1 + v2 + v3;
  float ss = v0*v0 + v1*v1 + v2*v2 + v3*v3;
  #pragma unroll
  for (int off = 32; off; off >>= 1) {
    s  += __shfl_xor(s, off);
    ss += __shfl_xor(ss, off);
  }
  const float mu = s * (1.0f / 256.0f);
  const float var = ss * (1.0f / 256.0f) - mu * mu;
  const float rs = rsqrtf(var + 1e-5f);
  const float4 gv = ((const float4*)g)[lane];
  const float4 bv = ((const float4*)b)[lane];
  long row;
  if (PART) {
    const int bI = t >> 12, l = t & 4095;
    const int hh = l >> 6, w2 = l & 63;
    const int wi = bI * 64 + (hh >> 3) * 8 + (w2 >> 3);
    const int n  = (hh & 7) * 8 + (w2 & 7);
    row = (long)wi * 64 + n;
  } else {
    row = t;
  }
  f16x4 o4;
  o4[0] = (f16)((v0 - mu) * rs * gv.x + bv.x);
  o4[1] = (f16)((v1 - mu) * rs * gv.y + bv.y);
  o4[2] = (f16)((v2 - mu) * rs * gv.z + bv.z);
  o4[3] = (f16)((v3 - mu) * rs * gv.w + bv.w);
  *(f16x4*)(out + row * 256 + lane * 4) = o4;
}

// ---------------- GEMM: C[M,N] = A[M,K] @ Bw[N,K]^T + bias, fused epilogues ----------------
// EPI 0: f16 out = v                               (qkv)
// EPI 1: f16 out[window-reversed row] = x + v      (proj -> x1 f16), resid fp32
// EPI 2: f16 out = gelu(v) (exp2-sigmoid form)     (fc1)
// EPI 3: f32 out = x1h + v                         (fc2 + residual, final), resid f16
// XCD-contiguous block remap. 3-stage counted-vmcnt pipeline: tiles t and t+1
// in flight; per iteration: vmcnt(4) [tile t landed, t+1 still flying] ->
// barrier -> ds_read frags -> lgkmcnt(0)+barrier [all waves done reading] ->
// stage tile t+2 into the freed buffer -> 16 MFMA. Last two tiles peeled.
// LDS stage layout XOR-swizzled both-sides so ds_read_b128 frag loads are
// conflict-free.
template<int EPI, int K>
__global__ __launch_bounds__(256) void gemm_bt(
    const f16* __restrict__ A, const f16* __restrict__ Bw,
    const float* __restrict__ bias, const float* __restrict__ residf,
    const f16* __restrict__ residh,
    f16* __restrict__ outh, float* __restrict__ outf, int N) {
  __shared__ f16 As[2][128 * 32];
  __shared__ f16 Bs[2][128 * 32];
  const int tid  = threadIdx.x;
  const int wid  = tid >> 6;
  const int lane = tid & 63;
  const int qd   = lane >> 4;       // quad 0..3
  const int l16  = lane & 15;
  // XCD-aware swizzle (nwg is always a multiple of 8 here)
  const int gx  = gridDim.x;
  const int nwg = gx * gridDim.y;
  const int g   = blockIdx.y * gx + blockIdx.x;
  const int gs  = (g & 7) * (nwg >> 3) + (g >> 3);
  const long tM = (long)(gs / gx) * 128;
  const int  tN = (gs % gx) * 128;
  const int srow = lane >> 2;       // 0..15
  // stage-side swizzle: column chunk XOR'd by (srow>>1)&3 (both-sides with read)
  const int scol = ((lane & 3) ^ ((srow >> 1) & 3)) * 8;  // pre-swizzled global col
  const int wm = (wid >> 1) * 64;
  const int wn = (wid & 1) * 64;
  const int rsw = (l16 >> 1) & 3;   // read-side swizzle for fragment loads

  f32x4 acc[4][4];
  #pragma unroll
  for (int i = 0; i < 4; ++i)
    #pragma unroll
    for (int j = 0; j < 4; ++j) acc[i][j] = (f32x4){0.f, 0.f, 0.f, 0.f};

  const int nt = K / 32;   // always even (8 or 32)
  f16x8 af[4], bf[4];

  auto stage_tile = [&](int tt) {
    const int k0 = tt * 32;
    f16* Ad = &As[tt & 1][0];
    f16* Bd = &Bs[tt & 1][0];
    #pragma unroll
    for (int u = 0; u < 2; ++u) {
      const int gidx = wid * 2 + u;
      const int row  = gidx * 16 + srow;
      __builtin_amdgcn_global_load_lds(AS1(A + (tM + row) * K + k0 + scol),
                                       AS3(&Ad[gidx * 512]), 16, 0, 0);
      __builtin_amdgcn_global_load_lds(AS1(Bw + (long)(tN + row) * K + k0 + scol),
                                       AS3(&Bd[gidx * 512]), 16, 0, 0);
    }
  };
  auto load_frags = [&](int cb) {
    #pragma unroll
    for (int i = 0; i < 4; ++i)
      af[i] = *(const f16x8*)&As[cb][(wm + i * 16 + l16) * 32 + ((qd ^ rsw) * 8)];
    #pragma unroll
    for (int j = 0; j < 4; ++j)
      bf[j] = *(const f16x8*)&Bs[cb][(wn + j * 16 + l16) * 32 + ((qd ^ rsw) * 8)];
  };
  auto do_mfma = [&]() {
    #pragma unroll
    for (int i = 0; i < 4; ++i)
      #pragma unroll
      for (int j = 0; j < 4; ++j)
        acc[i][j] = __builtin_amdgcn_mfma_f32_16x16x32_f16(af[i], bf[j], acc[i][j], 0, 0, 0);
  };

  // prologue: tiles 0 and 1 in flight
  stage_tile(0);
  stage_tile(1);

  for (int t = 0; t < nt - 2; ++t) {
    asm volatile("s_waitcnt vmcnt(4)" ::: "memory");   // tile t landed; t+1 in flight
    __builtin_amdgcn_s_barrier();
    load_frags(t & 1);
    asm volatile("s_waitcnt lgkmcnt(0)" ::: "memory"); // my reads of buf[t&1] done
    __builtin_amdgcn_s_barrier();                      // ALL waves' reads done
    stage_tile(t + 2);                                 // safe to overwrite buf[t&1]
    do_mfma();
  }
  // t = nt-2 (no further staging)
  asm volatile("s_waitcnt vmcnt(4)" ::: "memory");
  __builtin_amdgcn_s_barrier();
  load_frags(0);
  do_mfma();
  // t = nt-1
  asm volatile("s_waitcnt vmcnt(0)" ::: "memory");
  __builtin_amdgcn_s_barrier();
  load_frags(1);
  do_mfma();

  float bb[4];
  #pragma unroll
  for (int j = 0; j < 4; ++j) bb[j] = bias[tN + wn + j * 16 + l16];

  if (EPI == 3) {
    #pragma unroll
    for (int j = 0; j < 4; ++j) {
      const int col = tN + wn + j * 16 + l16;
      #pragma unroll
      for (int i = 0; i < 4; ++i) {
        #pragma unroll
        for (int r = 0; r < 4; ++r) {
          const long row = tM + wm + i * 16 + qd * 4 + r;
          const long off = row * 256 + col;
          outf[off] = (float)residh[off] + acc[i][j][r] + bb[j];
        }
      }
    }
  } else {
    // LDS-staged f16 epilogue; col XOR-swizzled by row to break 4-way write conflicts.
    // Last compute tile was buf1, so reusing As[0] here is race-free (plus barrier above).
    f16* slice = &As[0][0] + wid * 1024;  // per-wave 16x64 tile (2 KB)
    const int rrow = lane >> 3;          // 0..7
    const int seg  = lane & 7;           // 0..7
    #pragma unroll
    for (int i = 0; i < 4; ++i) {
      #pragma unroll
      for (int j = 0; j < 4; ++j) {
        #pragma unroll
        for (int r = 0; r < 4; ++r) {
          float v = acc[i][j][r] + bb[j];
          if (EPI == 2) {
            // gelu(v) = v * sigmoid(2*sqrt(2/pi)*(v + 0.044715 v^3)), via exp2:
            // w = -2*log2(e)*sqrt(2/pi)*(v + 0.044715 v^3)
            const float u2 = v * v;
            const float w  = v * (-2.3022082f - 0.10294324f * u2);
            const float e  = __builtin_amdgcn_exp2f(w);
            v = v * __builtin_amdgcn_rcpf(1.0f + e);
          }
          const int r16 = qd * 4 + r;
          slice[r16 * 64 + ((j * 16 + l16) ^ ((r16 & 7) << 3))] = (f16)v;
        }
      }
      __syncthreads();
      #pragma unroll
      for (int hrow = 0; hrow < 16; hrow += 8) {
        const int lrow = hrow + rrow;                       // 0..15
        const f16x8 v8 = *(const f16x8*)(slice + lrow * 64 + (seg ^ (lrow & 7)) * 8);
        const long grow = tM + wm + i * 16 + lrow;
        const int  gc   = tN + wn + seg * 8;
        if (EPI == 1) {
          const int rw = (int)grow;
          const int wi = rw >> 6, n = rw & 63;
          const int bI = wi >> 6, wloc = wi & 63;
          const int hh = (wloc >> 3) * 8 + (n >> 3);
          const int w2 = (wloc & 7) * 8 + (n & 7);
          const long prow = (long)bI * 4096 + hh * 64 + w2;
          const float* rp = residf + prow * 256 + gc;
          f16x8 o;
          #pragma unroll
          for (int k = 0; k < 8; ++k) o[k] = (f16)(rp[k] + (float)v8[k]);
          *(f16x8*)(outh + prow * 256 + gc) = o;
        } else {
          *(f16x8*)(outh + grow * N + gc) = v8;
        }
      }
      __syncthreads();
    }
  }
}

// ---------------- windowed attention: MFMA flash, one wave per (window, head) ----------------
// Per-wave private LDS slab (no __syncthreads needed):
//   [0, 4608)     : V^T f16, 32 rows (d) x stride 144B (72 f16), holds 64 m values/row
//   [4608, 12800) : P f16 64x64, row stride 128B, XOR-swizzled by ((row&7)<<4);
//                   later overlaid by O f16 64x32, row stride 80B
__global__ __launch_bounds__(256, 3) void attn_win(
    const f16* __restrict__ qkv, const float* __restrict__ bt,  // bt = T[8][64][64] pre-scaled
    f16* __restrict__ out) {
  __shared__ __align__(16) char SMEM[4 * 12800];
  const int wid = threadIdx.x >> 6, lane = threadIdx.x & 63;
  const int qd = lane >> 4, l16 = lane & 15;
  const int unit = blockIdx.x * 4 + wid;   // (window,head) unit within chunk
  const int wi = unit >> 3, h = unit & 7;
  char* W = SMEM + wid * 12800;
  f16* VT = (f16*)W;               // stride 72 f16 per d-row
  char* Pb = W + 4608;

  const f16* qbase = qkv + (long)wi * 64 * 768 + h * 32;

  // ---- Q/K fragments straight from global in MFMA A/B layout ----
  f16x8 qa[4], kb[4];
  #pragma unroll
  for (int i = 0; i < 4; ++i)
    qa[i] = *(const f16x8*)(qbase + (16 * i + l16) * 768 + qd * 8);
  #pragma unroll
  for (int j = 0; j < 4; ++j)
    kb[j] = *(const f16x8*)(qbase + 256 + (16 * j + l16) * 768 + qd * 8);

  // ---- stage V transposed into LDS: VT[d][m] ----
  #pragma unroll
  for (int it = 0; it < 4; ++it) {
    const f16x8 v8 = *(const f16x8*)(qbase + 512 + (16 * it + l16) * 768 + qd * 8);
    #pragma unroll
    for (int e = 0; e < 8; ++e)
      VT[(qd * 8 + e) * 72 + 16 * it + l16] = v8[e];
  }

  // ---- QK^T: S[n][m], C-layout: n = 16i+4qd+r, m = 16j+l16 ----
  f32x4 S[4][4];
  #pragma unroll
  for (int i = 0; i < 4; ++i)
    #pragma unroll
    for (int j = 0; j < 4; ++j) S[i][j] = (f32x4){0.f, 0.f, 0.f, 0.f};
  #pragma unroll
  for (int i = 0; i < 4; ++i)
    #pragma unroll
    for (int j = 0; j < 4; ++j)
      S[i][j] = __builtin_amdgcn_mfma_f32_16x16x32_f16(qa[i], kb[j], S[i][j], 0, 0, 0);

  // ---- scale (log2e folded) + bias from lane-ordered table ----
  const float SC = 0.17677669529663687f * 1.4426950408889634f;  // 1/sqrt(32)*log2e
  const float* Tb = bt + ((h * 64 + lane) << 6);
  #pragma unroll
  for (int i = 0; i < 4; ++i) {
    f32x4 b0 = *(const f32x4*)(Tb + i * 16);
    f32x4 b1 = *(const f32x4*)(Tb + i * 16 + 4);
    f32x4 b2 = *(const f32x4*)(Tb + i * 16 + 8);
    f32x4 b3 = *(const f32x4*)(Tb + i * 16 + 12);
    #pragma unroll
    for (int r = 0; r < 4; ++r) {
      S[i][0][r] = S[i][0][r] * SC + b0[r];
      S[i][1][r] = S[i][1][r] * SC + b1[r];
      S[i][2][r] = S[i][2][r] * SC + b2[r];
      S[i][3][r] = S[i][3][r] * SC + b3[r];
    }
  }

  // ---- softmax over m (cols): in-lane j-reduce + 16-lane butterfly ----
  float inv[4][4];
  #pragma unroll
  for (int i = 0; i < 4; ++i) {
    #pragma unroll
    for (int r = 0; r < 4; ++r) {
      float mx = fmaxf(fmaxf(S[i][0][r], S[i][1][r]), fmaxf(S[i][2][r], S[i][3][r]));
      #pragma unroll
      for (int msk = 1; msk < 16; msk <<= 1) mx = fmaxf(mx, __shfl_xor(mx, msk));
      float s0 = 0.f;
      #pragma unroll
      for (int j = 0; j < 4; ++j) {
        const float p = __builtin_amdgcn_exp2f(S[i][j][r] - mx);
        S[i][j][r] = p;
        s0 += p;
      }
      #pragma unroll
      for (int msk = 1; msk < 16; msk <<= 1) s0 += __shfl_xor(s0, msk);
      inv[i][r] = __builtin_amdgcn_rcpf(s0);
    }
  }

  // ---- P -> LDS f16 (unnormalized, <=1), XOR-swizzled by row ----
  #pragma unroll
  for (int i = 0; i < 4; ++i) {
    #pragma unroll
    for (int r = 0; r < 4; ++r) {
      const int n = 16 * i + 4 * qd + r;
      char* rowp = Pb + n * 128;
      const int sw = (n & 7) << 4;
      #pragma unroll
      for (int j = 0; j < 4; ++j)
        *(f16*)(rowp + ((j * 32 + l16 * 2) ^ sw)) = (f16)S[i][j][r];
    }
  }

  // ---- PV: O[64,32] = P @ V, A = P rows (LDS), B = V via VT rows (LDS) ----
  f32x4 O[4][2];
  #pragma unroll
  for (int i = 0; i < 4; ++i) {
    O[i][0] = (f32x4){0.f, 0.f, 0.f, 0.f};
    O[i][1] = (f32x4){0.f, 0.f, 0.f, 0.f};
  }
  #pragma unroll
  for (int kk = 0; kk < 2; ++kk) {
    f16x8 vb[2];
    #pragma unroll
    for (int jj = 0; jj < 2; ++jj)
      vb[jj] = *(const f16x8*)((const char*)W + (16 * jj + l16) * 144 + kk * 64 + qd * 16);
    #pragma unroll
    for (int i = 0; i < 4; ++i) {
      const f16x8 pa = *(const f16x8*)(Pb + (16 * i + l16) * 128 +
                                       ((kk * 64 + qd * 16) ^ ((l16 & 7) << 4)));
      #pragma unroll
      for (int jj = 0; jj < 2; ++jj)
        O[i][jj] = __builtin_amdgcn_mfma_f32_16x16x32_f16(pa, vb[jj], O[i][jj], 0, 0, 0);
    }
  }

  // ---- normalize (in-lane: same (i,qd,r) slot layout), stage O in LDS, store coalesced ----
  #pragma unroll
  for (int i = 0; i < 4; ++i) {
    #pragma unroll
    for (int jj = 0; jj < 2; ++jj) {
      #pragma unroll
      for (int r = 0; r < 4; ++r) {
        const int n = 16 * i + 4 * qd + r;
        *(f16*)(Pb + n * 80 + jj * 32 + l16 * 2) = (f16)(O[i][jj][r] * inv[i][r]);
      }
    }
  }
  #pragma unroll
  for (int it = 0; it < 4; ++it) {
    const int row = 16 * it + l16;
    const f16x8 o8 = *(const f16x8*)(Pb + row * 80 + qd * 16);
    *(f16x8*)(out + ((long)wi * 64 + row) * 256 + h * 32 + qd * 8) = o8;
  }
}

// ---------------- launch ----------------
extern "C" void kernel_launch(void* const* d_in, const int* in_sizes, int n_in,
                              void* d_out, int out_size, void* d_ws, size_t ws_size,
                              hipStream_t stream) {
  const float* x     = (const float*)d_in[0];
  const float* g1    = (const float*)d_in[2];
  const float* b1    = (const float*)d_in[3];
  const float* wqkv  = (const float*)d_in[4];
  const float* bqkv  = (const float*)d_in[5];
  const float* btab  = (const float*)d_in[6];
  const float* wproj = (const float*)d_in[7];
  const float* bproj = (const float*)d_in[8];
  const float* g2    = (const float*)d_in[9];
  const float* b2    = (const float*)d_in[10];
  const float* wfc1  = (const float*)d_in[11];
  const float* bfc1  = (const float*)d_in[12];
  const float* wfc2  = (const float*)d_in[13];
  const float* bfc2  = (const float*)d_in[14];
  float* out = (float*)d_out;

  char* ws = (char*)d_ws;
  // weights f16: 786432 elems = 1.5 MB at ws[0, 1.5MB); bias table T at [1.5MB, 1.625MB)
  f16* wgt   = (f16*)ws;
  f16* wq16  = wgt;
  f16* wp16  = wgt + 196608;
  f16* wf116 = wgt + 262144;
  f16* wf216 = wgt + 524288;
  float* Tbuf = (float*)(ws + 1572864);   // 8*64*64 f32 = 128 KB

  // Per-image f16 buffers: xn 2MB | qkv 6MB | x1 2MB | xn2 2MB ; h (8MB) reuses xn+qkv.
  int CH = 1;
  for (int cand = 32; cand >= 1; cand >>= 1) {
    const size_t need = 2097152ULL + (size_t)cand * 12582912ULL;
    if (need <= ws_size) { CH = cand; break; }
  }
  const int NC = 32 / CH;

  const size_t O_xn  = 2097152ULL;
  const size_t O_qkv = O_xn  + (size_t)CH * 2097152ULL;
  const size_t O_x1  = O_qkv + (size_t)CH * 6291456ULL;
  const size_t O_xn2 = O_x1  + (size_t)CH * 2097152ULL;
  f16* xnw  = (f16*)(ws + O_xn);    // ln1 out / attn out
  f16* qkvb = (f16*)(ws + O_qkv);
  f16* x1h  = (f16*)(ws + O_x1);
  f16* xn2  = (f16*)(ws + O_xn2);
  f16* hbuf = (f16*)(ws + O_xn);    // fc1 out: reuses xn+qkv (exactly CH*8MB)

  cvt_weights<<<3072, 256, 0, stream>>>(wqkv, wproj, wfc1, wfc2, wgt);
  prep_bias<<<128, 256, 0, stream>>>(btab, Tbuf);

  const long imgElems = 4096L * 256;   // fp32 elems per image
  for (int c = 0; c < NC; ++c) {
    const float* xc  = x   + (long)c * CH * imgElems;
    float*       oc  = out + (long)c * CH * imgElems;
    ln_rows<true, float><<<CH * 1024, 256, 0, stream>>>(xc, g1, b1, xnw);
    gemm_bt<0, 256><<<dim3(6, CH * 32), 256, 0, stream>>>(xnw, wq16, bqkv, nullptr, nullptr, qkvb, nullptr, 768);
    attn_win<<<CH * 128, 256, 0, stream>>>(qkvb, Tbuf, xnw);
    gemm_bt<1, 256><<<dim3(2, CH * 32), 256, 0, stream>>>(xnw, wp16, bproj, xc, nullptr, x1h, nullptr, 256);
    ln_rows<false, f16><<<CH * 1024, 256, 0, stream>>>(x1h, g2, b2, xn2);
    gemm_bt<2, 256><<<dim3(8, CH * 32), 256, 0, stream>>>(xn2, wf116, bfc1, nullptr, nullptr, hbuf, nullptr, 1024);
    gemm_bt<3, 1024><<<dim3(2, CH * 32), 256, 0, stream>>>(hbuf, wf216, bfc2, nullptr, x1h, nullptr, oc, 256);
  }
}

// Round 6
// 775.065 us; speedup vs baseline: 1.0343x; 1.0080x over previous
//
#include <hip/hip_runtime.h>
#include <hip/hip_bf16.h>
#include <hip/hip_fp16.h>

typedef _Float16 f16;
typedef __attribute__((ext_vector_type(8))) _Float16 f16x8;
typedef __attribute__((ext_vector_type(4))) _Float16 f16x4;
typedef __attribute__((ext_vector_type(2))) _Float16 f16x2;
typedef __attribute__((ext_vector_type(4))) float f32x4;

#define AS1(p) ((const __attribute__((address_space(1))) void*)(p))
#define AS3(p) ((__attribute__((address_space(3))) void*)(p))

// ---------------- weight fp32 -> f16 conversion (concatenated) ----------------
__global__ __launch_bounds__(256) void cvt_weights(
    const float* __restrict__ wq, const float* __restrict__ wp,
    const float* __restrict__ wf1, const float* __restrict__ wf2,
    f16* __restrict__ o) {
  int i = blockIdx.x * 256 + threadIdx.x;  // grid sized exactly 786432
  float v;
  if (i < 196608)       v = wq[i];
  else if (i < 262144)  v = wp[i - 196608];
  else if (i < 524288)  v = wf1[i - 262144];
  else                  v = wf2[i - 524288];
  o[i] = (f16)v;
}

// ---------------- bias table -> MFMA fragment-lane order, pre-scaled by log2e ----
// T[h][lane][i*16+j*4+r] = bias[idx(n,m)][h] * log2e, n=16i+4*(lane>>4)+r, m=16j+(lane&15)
__global__ __launch_bounds__(256) void prep_bias(
    const float* __restrict__ bt, float* __restrict__ T) {
  const int flat = blockIdx.x * 256 + threadIdx.x;   // grid = 128 -> 32768
  const int h = flat >> 12, l = (flat >> 6) & 63, s = flat & 63;
  const int i = s >> 4, j = (s >> 2) & 3, r = s & 3;
  const int n = 16 * i + 4 * (l >> 4) + r;
  const int m = 16 * j + (l & 15);
  const int idx = ((n >> 3) - (m >> 3) + 7) * 15 + ((n & 7) - (m & 7) + 7);
  T[flat] = bt[idx * 8 + h] * 1.4426950408889634f;
}

// ---------------- LayerNorm (one wave per 256-elem row) ----------------
// PART=true: write window-partitioned order; PART=false: natural row order
template<bool PART, typename TIN>
__global__ __launch_bounds__(256) void ln_rows(
    const TIN* __restrict__ x, const float* __restrict__ g,
    const float* __restrict__ b, f16* __restrict__ out) {
  const int t = blockIdx.x * 4 + (threadIdx.x >> 6);   // token row within chunk
  const int lane = threadIdx.x & 63;
  float v0, v1, v2, v3;
  if constexpr (sizeof(TIN) == 4) {
    const float4 v = ((const float4*)(x + (long)t * 256))[lane];
    v0 = v.x; v1 = v.y; v2 = v.z; v3 = v.w;
  } else {
    const f16x4 v = ((const f16x4*)(x + (long)t * 256))[lane];
    v0 = (float)v[0]; v1 = (float)v[1]; v2 = (float)v[2]; v3 = (float)v[3];
  }
  float s  = v0 + v1 + v2 + v3;
  float ss = v0*v0 + v1*v1 + v2*v2 + v3*v3;
  #pragma unroll
  for (int off = 32; off; off >>= 1) {
    s  += __shfl_xor(s, off);
    ss += __shfl_xor(ss, off);
  }
  const float mu = s * (1.0f / 256.0f);
  const float var = ss * (1.0f / 256.0f) - mu * mu;
  const float rs = rsqrtf(var + 1e-5f);
  const float4 gv = ((const float4*)g)[lane];
  const float4 bv = ((const float4*)b)[lane];
  long row;
  if (PART) {
    const int bI = t >> 12, l = t & 4095;
    const int hh = l >> 6, w2 = l & 63;
    const int wi = bI * 64 + (hh >> 3) * 8 + (w2 >> 3);
    const int n  = (hh & 7) * 8 + (w2 & 7);
    row = (long)wi * 64 + n;
  } else {
    row = t;
  }
  f16x4 o4;
  o4[0] = (f16)((v0 - mu) * rs * gv.x + bv.x);
  o4[1] = (f16)((v1 - mu) * rs * gv.y + bv.y);
  o4[2] = (f16)((v2 - mu) * rs * gv.z + bv.z);
  o4[3] = (f16)((v3 - mu) * rs * gv.w + bv.w);
  *(f16x4*)(out + row * 256 + lane * 4) = o4;
}

// ---------------- GEMM: C[M,N] = A[M,K] @ Bw[N,K]^T + bias, fused epilogues ----------------
// EPI 0: f16 out = v                               (qkv)
// EPI 1: f16 out[window-reversed row] = x + v      (proj -> x1 f16), resid fp32
// EPI 2: f16 out = gelu(v) (exp2-sigmoid form)     (fc1)
// EPI 3: f32 out = x1h + v                         (fc2 + residual, final), resid f16
// BK=64 K-step, double-buffered, counted vmcnt(8): tiles t and t+1 in flight;
// per iteration: vmcnt(8) [tile t landed, t+1 flying] -> barrier -> 16x
// ds_read_b128 frags -> lgkmcnt(0)+barrier [all waves done reading] -> stage
// tile t+2 -> 32 MFMA. One-iteration slack (~800+ cyc) covers L3/HBM latency.
// Tile rows are 128B (16-bank aliased), so chunk-XOR swizzle both-sides:
// stage chunk = (lane&7)^(lane>>3); read chunk = (kk*4+qd)^(row&7).
template<int EPI, int K>
__global__ __launch_bounds__(256) void gemm_bt(
    const f16* __restrict__ A, const f16* __restrict__ Bw,
    const float* __restrict__ bias, const float* __restrict__ residf,
    const f16* __restrict__ residh,
    f16* __restrict__ outh, float* __restrict__ outf, int N) {
  __shared__ f16 As[2][128 * 64];
  __shared__ f16 Bs[2][128 * 64];
  const int tid  = threadIdx.x;
  const int wid  = tid >> 6;
  const int lane = tid & 63;
  const int qd   = lane >> 4;       // quad 0..3
  const int l16  = lane & 15;
  // XCD-aware swizzle (nwg is always a multiple of 8 here)
  const int gx  = gridDim.x;
  const int nwg = gx * gridDim.y;
  const int g   = blockIdx.y * gx + blockIdx.x;
  const int gs  = (g & 7) * (nwg >> 3) + (g >> 3);
  const long tM = (long)(gs / gx) * 128;
  const int  tN = (gs % gx) * 128;
  // staging: each wave moves 4 groups of 1024B per matrix per tile.
  // group gidx covers rows gidx*8..gidx*8+7; lane -> row gidx*8+(lane>>3),
  // 16B chunk (lane&7), source column chunk XOR-swizzled by row&7 = lane>>3.
  const int sgrow = lane >> 3;                       // row within group, = row&7
  const int scol  = ((lane & 7) ^ sgrow) * 8;        // pre-swizzled global col (f16)
  const int wm = (wid >> 1) * 64;
  const int wn = (wid & 1) * 64;

  f32x4 acc[4][4];
  #pragma unroll
  for (int i = 0; i < 4; ++i)
    #pragma unroll
    for (int j = 0; j < 4; ++j) acc[i][j] = (f32x4){0.f, 0.f, 0.f, 0.f};

  const int nt = K / 64;   // 4 (K=256) or 16 (K=1024)
  f16x8 af[2][4], bf[2][4];

  auto stage_tile = [&](int tt) {
    const int k0 = tt * 64;
    f16* Ad = &As[tt & 1][0];
    f16* Bd = &Bs[tt & 1][0];
    #pragma unroll
    for (int u = 0; u < 4; ++u) {
      const int gidx = wid * 4 + u;                  // group 0..15
      const int row  = gidx * 8 + sgrow;             // 0..127
      __builtin_amdgcn_global_load_lds(AS1(A + (tM + row) * K + k0 + scol),
                                       AS3(&Ad[gidx * 512]), 16, 0, 0);
      __builtin_amdgcn_global_load_lds(AS1(Bw + (long)(tN + row) * K + k0 + scol),
                                       AS3(&Bd[gidx * 512]), 16, 0, 0);
    }
  };
  auto load_frags = [&](int cb) {
    #pragma unroll
    for (int kk = 0; kk < 2; ++kk) {
      #pragma unroll
      for (int i = 0; i < 4; ++i) {
        const int row = wm + i * 16 + l16;
        af[kk][i] = *(const f16x8*)&As[cb][row * 64 + (((kk << 2) | qd) ^ (row & 7)) * 8];
      }
      #pragma unroll
      for (int j = 0; j < 4; ++j) {
        const int row = wn + j * 16 + l16;
        bf[kk][j] = *(const f16x8*)&Bs[cb][row * 64 + (((kk << 2) | qd) ^ (row & 7)) * 8];
      }
    }
  };
  auto do_mfma = [&]() {
    #pragma unroll
    for (int kk = 0; kk < 2; ++kk)
      #pragma unroll
      for (int i = 0; i < 4; ++i)
        #pragma unroll
        for (int j = 0; j < 4; ++j)
          acc[i][j] = __builtin_amdgcn_mfma_f32_16x16x32_f16(af[kk][i], bf[kk][j], acc[i][j], 0, 0, 0);
  };

  // prologue: tiles 0 and 1 in flight (8 loads each per wave)
  stage_tile(0);
  stage_tile(1);

  for (int t = 0; t < nt - 2; ++t) {
    asm volatile("s_waitcnt vmcnt(8)" ::: "memory");   // tile t landed; t+1 in flight
    __builtin_amdgcn_s_barrier();
    load_frags(t & 1);
    asm volatile("s_waitcnt lgkmcnt(0)" ::: "memory"); // my reads of buf[t&1] done
    __builtin_amdgcn_s_barrier();                      // ALL waves' reads done
    stage_tile(t + 2);                                 // safe to overwrite buf[t&1]
    do_mfma();
  }
  // t = nt-2 (no further staging)
  asm volatile("s_waitcnt vmcnt(8)" ::: "memory");
  __builtin_amdgcn_s_barrier();
  load_frags(nt & 1);        // (nt-2)&1 == nt&1
  do_mfma();
  // t = nt-1
  asm volatile("s_waitcnt vmcnt(0)" ::: "memory");
  __builtin_amdgcn_s_barrier();
  load_frags((nt - 1) & 1);
  do_mfma();

  float bb[4];
  #pragma unroll
  for (int j = 0; j < 4; ++j) bb[j] = bias[tN + wn + j * 16 + l16];

  if (EPI == 3) {
    #pragma unroll
    for (int j = 0; j < 4; ++j) {
      const int col = tN + wn + j * 16 + l16;
      #pragma unroll
      for (int i = 0; i < 4; ++i) {
        #pragma unroll
        for (int r = 0; r < 4; ++r) {
          const long row = tM + wm + i * 16 + qd * 4 + r;
          const long off = row * 256 + col;
          outf[off] = (float)residh[off] + acc[i][j][r] + bb[j];
        }
      }
    }
  } else {
    // LDS-staged f16 epilogue; col XOR-swizzled by row to break 4-way write conflicts.
    __syncthreads();                      // all waves past K-loop before reusing As
    f16* slice = &As[0][0] + wid * 1024;  // per-wave 16x64 tile (2 KB)
    const int rrow = lane >> 3;          // 0..7
    const int seg  = lane & 7;           // 0..7
    #pragma unroll
    for (int i = 0; i < 4; ++i) {
      #pragma unroll
      for (int j = 0; j < 4; ++j) {
        #pragma unroll
        for (int r = 0; r < 4; ++r) {
          float v = acc[i][j][r] + bb[j];
          if (EPI == 2) {
            // gelu(v) = v * sigmoid(2*sqrt(2/pi)*(v + 0.044715 v^3)), via exp2
            const float u2 = v * v;
            const float w  = v * (-2.3022082f - 0.10294324f * u2);
            const float e  = __builtin_amdgcn_exp2f(w);
            v = v * __builtin_amdgcn_rcpf(1.0f + e);
          }
          const int r16 = qd * 4 + r;
          slice[r16 * 64 + ((j * 16 + l16) ^ ((r16 & 7) << 3))] = (f16)v;
        }
      }
      __syncthreads();
      #pragma unroll
      for (int hrow = 0; hrow < 16; hrow += 8) {
        const int lrow = hrow + rrow;                       // 0..15
        const f16x8 v8 = *(const f16x8*)(slice + lrow * 64 + (seg ^ (lrow & 7)) * 8);
        const long grow = tM + wm + i * 16 + lrow;
        const int  gc   = tN + wn + seg * 8;
        if (EPI == 1) {
          const int rw = (int)grow;
          const int wi = rw >> 6, n = rw & 63;
          const int bI = wi >> 6, wloc = wi & 63;
          const int hh = (wloc >> 3) * 8 + (n >> 3);
          const int w2 = (wloc & 7) * 8 + (n & 7);
          const long prow = (long)bI * 4096 + hh * 64 + w2;
          const float* rp = residf + prow * 256 + gc;
          f16x8 o;
          #pragma unroll
          for (int k = 0; k < 8; ++k) o[k] = (f16)(rp[k] + (float)v8[k]);
          *(f16x8*)(outh + prow * 256 + gc) = o;
        } else {
          *(f16x8*)(outh + grow * N + gc) = v8;
        }
      }
      __syncthreads();
    }
  }
}

// ---------------- windowed attention: MFMA flash, one wave per (window, head) ----------------
// Per-wave private LDS slab (no __syncthreads needed):
//   [0, 4608)     : V^T f16, 32 rows (d) x stride 144B (72 f16), holds 64 m values/row
//   [4608, 12800) : P f16 64x64, row stride 128B, XOR-swizzled by ((row&7)<<4);
//                   later overlaid by O f16 64x32, row stride 80B
__global__ __launch_bounds__(256, 3) void attn_win(
    const f16* __restrict__ qkv, const float* __restrict__ bt,  // bt = T[8][64][64] pre-scaled
    f16* __restrict__ out) {
  __shared__ __align__(16) char SMEM[4 * 12800];
  const int wid = threadIdx.x >> 6, lane = threadIdx.x & 63;
  const int qd = lane >> 4, l16 = lane & 15;
  const int unit = blockIdx.x * 4 + wid;   // (window,head) unit within chunk
  const int wi = unit >> 3, h = unit & 7;
  char* W = SMEM + wid * 12800;
  f16* VT = (f16*)W;               // stride 72 f16 per d-row
  char* Pb = W + 4608;

  const f16* qbase = qkv + (long)wi * 64 * 768 + h * 32;

  // ---- Q/K fragments straight from global in MFMA A/B layout ----
  f16x8 qa[4], kb[4];
  #pragma unroll
  for (int i = 0; i < 4; ++i)
    qa[i] = *(const f16x8*)(qbase + (16 * i + l16) * 768 + qd * 8);
  #pragma unroll
  for (int j = 0; j < 4; ++j)
    kb[j] = *(const f16x8*)(qbase + 256 + (16 * j + l16) * 768 + qd * 8);

  // ---- stage V transposed into LDS: VT[d][m] ----
  #pragma unroll
  for (int it = 0; it < 4; ++it) {
    const f16x8 v8 = *(const f16x8*)(qbase + 512 + (16 * it + l16) * 768 + qd * 8);
    #pragma unroll
    for (int e = 0; e < 8; ++e)
      VT[(qd * 8 + e) * 72 + 16 * it + l16] = v8[e];
  }

  // ---- QK^T: S[n][m], C-layout: n = 16i+4qd+r, m = 16j+l16 ----
  f32x4 S[4][4];
  #pragma unroll
  for (int i = 0; i < 4; ++i)
    #pragma unroll
    for (int j = 0; j < 4; ++j) S[i][j] = (f32x4){0.f, 0.f, 0.f, 0.f};
  #pragma unroll
  for (int i = 0; i < 4; ++i)
    #pragma unroll
    for (int j = 0; j < 4; ++j)
      S[i][j] = __builtin_amdgcn_mfma_f32_16x16x32_f16(qa[i], kb[j], S[i][j], 0, 0, 0);

  // ---- scale (log2e folded) + bias from lane-ordered table ----
  const float SC = 0.17677669529663687f * 1.4426950408889634f;  // 1/sqrt(32)*log2e
  const float* Tb = bt + ((h * 64 + lane) << 6);
  #pragma unroll
  for (int i = 0; i < 4; ++i) {
    f32x4 b0 = *(const f32x4*)(Tb + i * 16);
    f32x4 b1 = *(const f32x4*)(Tb + i * 16 + 4);
    f32x4 b2 = *(const f32x4*)(Tb + i * 16 + 8);
    f32x4 b3 = *(const f32x4*)(Tb + i * 16 + 12);
    #pragma unroll
    for (int r = 0; r < 4; ++r) {
      S[i][0][r] = S[i][0][r] * SC + b0[r];
      S[i][1][r] = S[i][1][r] * SC + b1[r];
      S[i][2][r] = S[i][2][r] * SC + b2[r];
      S[i][3][r] = S[i][3][r] * SC + b3[r];
    }
  }

  // ---- softmax over m (cols): in-lane j-reduce + 16-lane butterfly ----
  float inv[4][4];
  #pragma unroll
  for (int i = 0; i < 4; ++i) {
    #pragma unroll
    for (int r = 0; r < 4; ++r) {
      float mx = fmaxf(fmaxf(S[i][0][r], S[i][1][r]), fmaxf(S[i][2][r], S[i][3][r]));
      #pragma unroll
      for (int msk = 1; msk < 16; msk <<= 1) mx = fmaxf(mx, __shfl_xor(mx, msk));
      float s0 = 0.f;
      #pragma unroll
      for (int j = 0; j < 4; ++j) {
        const float p = __builtin_amdgcn_exp2f(S[i][j][r] - mx);
        S[i][j][r] = p;
        s0 += p;
      }
      #pragma unroll
      for (int msk = 1; msk < 16; msk <<= 1) s0 += __shfl_xor(s0, msk);
      inv[i][r] = __builtin_amdgcn_rcpf(s0);
    }
  }

  // ---- P -> LDS f16 (unnormalized, <=1), XOR-swizzled by row ----
  #pragma unroll
  for (int i = 0; i < 4; ++i) {
    #pragma unroll
    for (int r = 0; r < 4; ++r) {
      const int n = 16 * i + 4 * qd + r;
      char* rowp = Pb + n * 128;
      const int sw = (n & 7) << 4;
      #pragma unroll
      for (int j = 0; j < 4; ++j)
        *(f16*)(rowp + ((j * 32 + l16 * 2) ^ sw)) = (f16)S[i][j][r];
    }
  }

  // ---- PV: O[64,32] = P @ V, A = P rows (LDS), B = V via VT rows (LDS) ----
  f32x4 O[4][2];
  #pragma unroll
  for (int i = 0; i < 4; ++i) {
    O[i][0] = (f32x4){0.f, 0.f, 0.f, 0.f};
    O[i][1] = (f32x4){0.f, 0.f, 0.f, 0.f};
  }
  #pragma unroll
  for (int kk = 0; kk < 2; ++kk) {
    f16x8 vb[2];
    #pragma unroll
    for (int jj = 0; jj < 2; ++jj)
      vb[jj] = *(const f16x8*)((const char*)W + (16 * jj + l16) * 144 + kk * 64 + qd * 16);
    #pragma unroll
    for (int i = 0; i < 4; ++i) {
      const f16x8 pa = *(const f16x8*)(Pb + (16 * i + l16) * 128 +
                                       ((kk * 64 + qd * 16) ^ ((l16 & 7) << 4)));
      #pragma unroll
      for (int jj = 0; jj < 2; ++jj)
        O[i][jj] = __builtin_amdgcn_mfma_f32_16x16x32_f16(pa, vb[jj], O[i][jj], 0, 0, 0);
    }
  }

  // ---- normalize (in-lane: same (i,qd,r) slot layout), stage O in LDS, store coalesced ----
  #pragma unroll
  for (int i = 0; i < 4; ++i) {
    #pragma unroll
    for (int jj = 0; jj < 2; ++jj) {
      #pragma unroll
      for (int r = 0; r < 4; ++r) {
        const int n = 16 * i + 4 * qd + r;
        *(f16*)(Pb + n * 80 + jj * 32 + l16 * 2) = (f16)(O[i][jj][r] * inv[i][r]);
      }
    }
  }
  #pragma unroll
  for (int it = 0; it < 4; ++it) {
    const int row = 16 * it + l16;
    const f16x8 o8 = *(const f16x8*)(Pb + row * 80 + qd * 16);
    *(f16x8*)(out + ((long)wi * 64 + row) * 256 + h * 32 + qd * 8) = o8;
  }
}

// ---------------- launch ----------------
extern "C" void kernel_launch(void* const* d_in, const int* in_sizes, int n_in,
                              void* d_out, int out_size, void* d_ws, size_t ws_size,
                              hipStream_t stream) {
  const float* x     = (const float*)d_in[0];
  const float* g1    = (const float*)d_in[2];
  const float* b1    = (const float*)d_in[3];
  const float* wqkv  = (const float*)d_in[4];
  const float* bqkv  = (const float*)d_in[5];
  const float* btab  = (const float*)d_in[6];
  const float* wproj = (const float*)d_in[7];
  const float* bproj = (const float*)d_in[8];
  const float* g2    = (const float*)d_in[9];
  const float* b2    = (const float*)d_in[10];
  const float* wfc1  = (const float*)d_in[11];
  const float* bfc1  = (const float*)d_in[12];
  const float* wfc2  = (const float*)d_in[13];
  const float* bfc2  = (const float*)d_in[14];
  float* out = (float*)d_out;

  char* ws = (char*)d_ws;
  // weights f16: 786432 elems = 1.5 MB at ws[0, 1.5MB); bias table T at [1.5MB, 1.625MB)
  f16* wgt   = (f16*)ws;
  f16* wq16  = wgt;
  f16* wp16  = wgt + 196608;
  f16* wf116 = wgt + 262144;
  f16* wf216 = wgt + 524288;
  float* Tbuf = (float*)(ws + 1572864);   // 8*64*64 f32 = 128 KB

  // Per-image f16 buffers: xn 2MB | qkv 6MB | x1 2MB | xn2 2MB ; h (8MB) reuses xn+qkv.
  int CH = 1;
  for (int cand = 32; cand >= 1; cand >>= 1) {
    const size_t need = 2097152ULL + (size_t)cand * 12582912ULL;
    if (need <= ws_size) { CH = cand; break; }
  }
  const int NC = 32 / CH;

  const size_t O_xn  = 2097152ULL;
  const size_t O_qkv = O_xn  + (size_t)CH * 2097152ULL;
  const size_t O_x1  = O_qkv + (size_t)CH * 6291456ULL;
  const size_t O_xn2 = O_x1  + (size_t)CH * 2097152ULL;
  f16* xnw  = (f16*)(ws + O_xn);    // ln1 out / attn out
  f16* qkvb = (f16*)(ws + O_qkv);
  f16* x1h  = (f16*)(ws + O_x1);
  f16* xn2  = (f16*)(ws + O_xn2);
  f16* hbuf = (f16*)(ws + O_xn);    // fc1 out: reuses xn+qkv (exactly CH*8MB)

  cvt_weights<<<3072, 256, 0, stream>>>(wqkv, wproj, wfc1, wfc2, wgt);
  prep_bias<<<128, 256, 0, stream>>>(btab, Tbuf);

  const long imgElems = 4096L * 256;   // fp32 elems per image
  for (int c = 0; c < NC; ++c) {
    const float* xc  = x   + (long)c * CH * imgElems;
    float*       oc  = out + (long)c * CH * imgElems;
    ln_rows<true, float><<<CH * 1024, 256, 0, stream>>>(xc, g1, b1, xnw);
    gemm_bt<0, 256><<<dim3(6, CH * 32), 256, 0, stream>>>(xnw, wq16, bqkv, nullptr, nullptr, qkvb, nullptr, 768);
    attn_win<<<CH * 128, 256, 0, stream>>>(qkvb, Tbuf, xnw);
    gemm_bt<1, 256><<<dim3(2, CH * 32), 256, 0, stream>>>(xnw, wp16, bproj, xc, nullptr, x1h, nullptr, 256);
    ln_rows<false, f16><<<CH * 1024, 256, 0, stream>>>(x1h, g2, b2, xn2);
    gemm_bt<2, 256><<<dim3(8, CH * 32), 256, 0, stream>>>(xn2, wf116, bfc1, nullptr, nullptr, hbuf, nullptr, 1024);
    gemm_bt<3, 1024><<<dim3(2, CH * 32), 256, 0, stream>>>(hbuf, wf216, bfc2, nullptr, x1h, nullptr, oc, 256);
  }
}